// Round 9
// baseline (258.652 us; speedup 1.0000x reference)
//
#include <hip/hip_runtime.h>
#include <cstdint>
#include <cstddef>

// PointerNetwork: B=256, S=512, H=128, CHAR/CLASS=10, OUT=64, WE=32
// R10 design = R6 (best measured: 115.6 us k_lstm / 203.3 total) with ONE
// change: the L1 MFMAs are fused into the L2 k-loop's ks=4..7 iterations,
// reusing the identical A-operand LDS reads (hc[kb+32ks] == hc[128+kb+32(ks-4)])
// -> 8 instead of 12 ds_read_b128 per thread-step (-33% LDS-pipe load).
// Accumulation order unchanged -> bit-identical numerics.
// Weight residency is left ENTIRELY to the compiler (R7/R8/R9 all proved
// explicit pinning/streaming regresses).

#define HIST 128
#define HPAD 132

typedef _Float16 f16x8 __attribute__((ext_vector_type(8)));
typedef float    f32x4 __attribute__((ext_vector_type(4)));

__device__ __forceinline__ f16x8 as_h8(const uint4& v) {
    f16x8 r; __builtin_memcpy(&r, &v, 16); return r;
}

#define MFMA16(a, b, c) __builtin_amdgcn_mfma_f32_16x16x32_f16((a), (b), (c), 0, 0, 0)

__device__ __forceinline__ float fast_rcp(float x) {
#if __has_builtin(__builtin_amdgcn_rcpf)
    return __builtin_amdgcn_rcpf(x);
#else
    return 1.f / x;
#endif
}
__device__ __forceinline__ float sigm(float x) {
    x = fminf(fmaxf(x, -30.f), 30.f);
    return fast_rcp(1.f + __expf(-x));
}
__device__ __forceinline__ float tanh_fast(float x) {
    x = fminf(fmaxf(x, -15.f), 15.f);
    float e = __expf(-2.f * x);
    return (1.f - e) * fast_rcp(1.f + e);
}

// ---------------- P0: merged prep: XW1 table + MFMA B-frag packing -----------
// blocks 0..9: XW1 row for word id = blk.  blocks 10..57: pack WF.
// k_lstm thread thr = (w=thr>>6, l=thr&63); frag f: 0..31 L2 (j=f>>3, ks=f&7),
// 32..47 L1 (j=(f-32)>>2, ks=(f-32)&3). col = j*128 + 16*w + (l&15);
// elems e: k = ks*32 + 8*(l>>4) + e.
// L2 k<128 -> l2_Wh row k (h2 half), else l2_Wx row k-128 (h1n half).
__global__ __launch_bounds__(512) void k_prep(
    const float* __restrict__ emb_char, const float* __restrict__ emb_word,
    const float* __restrict__ Wwc, const float* __restrict__ bwc,
    const float* __restrict__ l1_Wx, const float* __restrict__ l1_b,
    const float* __restrict__ l1_Wh, const float* __restrict__ l2_Wx,
    const float* __restrict__ l2_Wh,
    float* __restrict__ XW1, uint4* __restrict__ WF)
{
    const int blk = blockIdx.x;
    const int T = threadIdx.x;
    if (blk < 10) {
        __shared__ float xw[64];
        if (T < 64) {
            float acc = emb_char[T] + bwc[T];   // emb_char row 0 (active steps have char==0)
            for (int m = 0; m < 32; ++m) acc += emb_word[blk * 32 + m] * Wwc[m * 64 + T];
            xw[T] = acc;
        }
        __syncthreads();
        float acc = l1_b[T];
        for (int k = 0; k < 64; ++k) acc += xw[k] * l1_Wx[k * 512 + T];
        XW1[blk * 512 + T] = acc;
    } else {
        const int gid = (blk - 10) * 512 + T;   // 0..24575 frags
        const int thr = gid / 48;
        const int f   = gid - thr * 48;
        const int w   = thr >> 6, l = thr & 63;
        const int kb  = 8 * (l >> 4);
        const bool isL2 = (f < 32);
        int j, ks;
        if (isL2) { j = f >> 3; ks = f & 7; }
        else      { const int f2 = f - 32; j = f2 >> 2; ks = f2 & 3; }
        const int col = j * 128 + 16 * w + (l & 15);
        union { uint4 qv; _Float16 h[8]; } o;
        for (int e = 0; e < 8; ++e) {
            const int k = ks * 32 + kb + e;
            float v;
            if (isL2) v = (k < 128) ? l2_Wh[k * 512 + col] : l2_Wx[(k - 128) * 512 + col];
            else      v = l1_Wh[k * 512 + col];
            o.h[e] = (_Float16)v;
        }
        WF[gid] = o.qv;   // gid == thr*48 + f
    }
}

// ---------------- main kernel: MFMA recurrence + fused epilogue --------------
__global__ __launch_bounds__(512, 2) void k_lstm(
    const int* __restrict__ char_ids, const int* __restrict__ word_ids,
    const int* __restrict__ subject_ids,
    const float* __restrict__ XW1, const uint4* __restrict__ WF,
    const float* __restrict__ l2_b,
    const float* __restrict__ beta_W, const float* __restrict__ beta_b,
    const float* __restrict__ gamma_W, const float* __restrict__ gamma_b,
    const float* __restrict__ sub_W, const float* __restrict__ sub_b,
    const float* __restrict__ po_W, const float* __restrict__ po_b,
    float* __restrict__ out)
{
    const int b    = blockIdx.x;
    const int T    = threadIdx.x;   // 0..511
    const int lane = T & 63;
    const int wv   = T >> 6;        // wave 0..7
    const int kb   = 8 * (lane >> 4);          // k-slab base within 32
    const int unit = 16 * wv + (lane & 15);    // this lane's unit (lanes<16 real)
    const bool g16 = (lane < 16);

    __shared__ int   charL[512];
    __shared__ int   wordL[512];
    __shared__ float XW1L[5120];                        // 10x512 XW1 table
    __shared__ __align__(16) _Float16 hcat[2][256];     // [h2 | h1n] dbuf
    __shared__ short wlist[512];
    __shared__ unsigned short idxL[512];
    __shared__ int   ccnt[8];
    __shared__ __align__(16) float hl[HIST * HPAD];     // h-history (f32)
    // epilogue workspace
    __shared__ float A[20][132];
    __shared__ float K1[20], K2[20];
    __shared__ float gm[128], bt[128];
    __shared__ float urs[HIST][2];
    __shared__ float povals[HIST * 20];
    __shared__ float subv[HIST * 2];
    __shared__ float swl[256];
    __shared__ float subj[256];

    charL[T] = char_ids[b * 512 + T];
    wordL[T] = word_ids[b * 512 + T];
#pragma unroll
    for (int i = 0; i < 10; ++i) XW1L[i * 512 + T] = XW1[i * 512 + T];
    __syncthreads();

    // compact active-step list (ordered) + slot map
    const bool act = (charL[T] == 0);
    const unsigned long long bmask = __ballot(act);
    if (lane == 0) ccnt[wv] = (int)__popcll(bmask);
    __syncthreads();
    int base = 0;
    for (int i = 0; i < wv; ++i) base += ccnt[i];
    int tot = base;
    for (int i = wv; i < 8; ++i) tot += ccnt[i];
    if (act) {
        const int pos = base + (int)__popcll(bmask & ((1ull << lane) - 1ull));
        wlist[pos] = (short)wordL[T];
    }
    {
        const int cin = base + (int)__popcll(bmask & ((2ull << lane) - 1ull));
        idxL[T] = (unsigned short)(cin < HIST - 1 ? cin : HIST - 1);
    }
    const int nact = tot;

    // init state
    if (T < 128) {
        hcat[0][T] = (_Float16)0.f;   // h2(-1) = 0
        hl[T]      = 0.f;             // slot 0 = zeros
    }
    float c1 = 0.f, c2 = 0.f;         // valid on lanes<16
    const float l2b0 = l2_b[unit];
    const float l2b1 = l2_b[128 + unit];
    const float l2b2 = l2_b[256 + unit];
    const float l2b3 = l2_b[384 + unit];

    // persistent MFMA B-fragments (48 x uint4 = 192 regs; residency left to
    // the compiler -- R7/R8/R9 proved explicit pin/stream regresses)
    uint4 wf[48];
    {
        const uint4* p = WF + (size_t)T * 48;
#pragma unroll
        for (int i = 0; i < 48; ++i) wf[i] = p[i];
    }
    __syncthreads();

    // prologue: L1 gates for step 0 (h1 == 0 -> z = xw)
    if (nact > 0) {
        const int w0_ = wlist[0];
        const float zi = XW1L[w0_ * 512 + unit];
        const float zg = XW1L[w0_ * 512 + 256 + unit];
        const float zo = XW1L[w0_ * 512 + 384 + unit];
        c1 = sigm(zi) * tanh_fast(zg);            // c1_old == 0
        const float h1n = sigm(zo) * tanh_fast(c1);
        if (g16) hcat[0][128 + unit] = (_Float16)h1n;
        __syncthreads();
    }

    // superphase a: hcat[cur] = [h2(a-1) | h1n(a)].
    //   L2(a): z = bias + hcat[cur]*W2  -> h2(a) -> hcat[nxt][unit] + hl
    //   L1(a+1): z = xw(a+1) + h1n(a)*W1h -> h1n(a+1) -> hcat[nxt][128+unit]
    // L1's A-operands hc[128+kb+32*ks1] == L2's ks=4..7 operands -> fused loop
    // reuses each ds_read_b128 for 8 MFMAs (8 instead of 12 reads/step).
    int cur = 0;
    for (int a = 0; a < nact; ++a) {
        const _Float16* hc = hcat[cur];
        _Float16*       hn = hcat[cur ^ 1];
        const bool more = (a + 1 < nact);
        const int wid = more ? wlist[a + 1] : 0;

        f32x4 acc0 = {l2b0, 0.f, 0.f, 0.f};
        f32x4 acc1 = {l2b1, 0.f, 0.f, 0.f};
        f32x4 acc2 = {l2b2, 0.f, 0.f, 0.f};
        f32x4 acc3 = {l2b3, 0.f, 0.f, 0.f};
        f32x4 r0 = {XW1L[wid * 512 + unit],       0.f, 0.f, 0.f};
        f32x4 r1 = {XW1L[wid * 512 + 128 + unit], 0.f, 0.f, 0.f};
        f32x4 r2 = {XW1L[wid * 512 + 256 + unit], 0.f, 0.f, 0.f};
        f32x4 r3 = {XW1L[wid * 512 + 384 + unit], 0.f, 0.f, 0.f};

#pragma unroll
        for (int ks = 0; ks < 4; ++ks) {
            const f16x8 aa = *(const f16x8*)&hc[kb + 32 * ks];
            acc0 = MFMA16(aa, as_h8(wf[0 * 8 + ks]), acc0);
            acc1 = MFMA16(aa, as_h8(wf[1 * 8 + ks]), acc1);
            acc2 = MFMA16(aa, as_h8(wf[2 * 8 + ks]), acc2);
            acc3 = MFMA16(aa, as_h8(wf[3 * 8 + ks]), acc3);
        }
#pragma unroll
        for (int ks = 4; ks < 8; ++ks) {
            const f16x8 aa = *(const f16x8*)&hc[kb + 32 * ks];
            acc0 = MFMA16(aa, as_h8(wf[0 * 8 + ks]), acc0);
            acc1 = MFMA16(aa, as_h8(wf[1 * 8 + ks]), acc1);
            acc2 = MFMA16(aa, as_h8(wf[2 * 8 + ks]), acc2);
            acc3 = MFMA16(aa, as_h8(wf[3 * 8 + ks]), acc3);
            r0 = MFMA16(aa, as_h8(wf[32 + 0 * 4 + (ks - 4)]), r0);
            r1 = MFMA16(aa, as_h8(wf[32 + 1 * 4 + (ks - 4)]), r1);
            r2 = MFMA16(aa, as_h8(wf[32 + 2 * 4 + (ks - 4)]), r2);
            r3 = MFMA16(aa, as_h8(wf[32 + 3 * 4 + (ks - 4)]), r3);
        }

        if (g16) {
            c2 = sigm(acc1[0]) * c2 + sigm(acc0[0]) * tanh_fast(acc2[0]);
            const float h2v = sigm(acc3[0]) * tanh_fast(c2);
            hn[unit] = (_Float16)h2v;
            const int slot = (a + 1 < HIST - 1) ? a + 1 : HIST - 1;
            hl[slot * HPAD + unit] = h2v;
        }
        if (more && g16) {
            c1 = sigm(r1[0]) * c1 + sigm(r0[0]) * tanh_fast(r2[0]);
            const float h1n = sigm(r3[0]) * tanh_fast(c1);
            hn[128 + unit] = (_Float16)h1n;
        }
        __syncthreads();
        cur ^= 1;
    }

    // ================= fused epilogue (identical to R5/R6) ===================
    if (T < 256) {
        swl[T] = sub_W[T];
        const int uu = T & 127, half = T >> 7;
        const int sidx = subject_ids[b * 2 + half];
        const int slot = idxL[sidx];
        subj[T] = hl[slot * HPAD + uu];
    }
    __syncthreads();

    if (T < 256) {
        const int uu = T & 127, half = T >> 7;
        const float* __restrict__ W = half ? gamma_W : beta_W;
        float acc = half ? gamma_b[uu] : beta_b[uu];
        for (int c = 0; c < 256; ++c) acc += subj[c] * W[c * 128 + uu];
        if (half) gm[uu] = acc;
        else      bt[uu] = acc;
    }
    __syncthreads();

    for (int i = T; i < 2560; i += 512) {
        const int o = i >> 7, c = i & 127;
        A[o][c] = gm[c] * po_W[c * 20 + o];
    }
    if (T < 20) {
        float k1 = po_b[T], k2 = 0.f;
        for (int c = 0; c < 128; ++c) {
            const float pw = po_W[c * 20 + T];
            k1 += bt[c] * pw;
            k2 += gm[c] * pw;
        }
        K1[T] = k1; K2[T] = k2;
    }
    const int nslot = (int)idxL[511] + 1;
    const float sb0 = sub_b[0], sb1 = sub_b[1];
    for (int s = T; s < nslot; s += 512) {
        const float4* hp4 = (const float4*)&hl[s * HPAD];
        float sum = 0.f, s2 = 0.f, sub0 = sb0, sub1 = sb1;
        for (int c4 = 0; c4 < 32; ++c4) {
            const float4 h = hp4[c4];
            sum += (h.x + h.y) + (h.z + h.w);
            s2  += h.x * h.x + h.y * h.y + h.z * h.z + h.w * h.w;
            const int c = 4 * c4;
            sub0 += h.x * swl[2 * c] + h.y * swl[2 * c + 2] + h.z * swl[2 * c + 4] + h.w * swl[2 * c + 6];
            sub1 += h.x * swl[2 * c + 1] + h.y * swl[2 * c + 3] + h.z * swl[2 * c + 5] + h.w * swl[2 * c + 7];
        }
        const float mu = sum * (1.f / 128.f);
        const float vv = fmaxf(s2 * (1.f / 128.f) - mu * mu, 0.f);
        urs[s][0] = mu;
        urs[s][1] = 1.f / sqrtf(vv + 1e-12f);
        subv[2 * s] = sub0; subv[2 * s + 1] = sub1;
    }
    __syncthreads();

    for (int i = T; i < nslot * 20; i += 512) {
        const int s = i / 20, o = i - 20 * s;
        const float mu = urs[s][0], rs = urs[s][1];
        const float4* hp4 = (const float4*)&hl[s * HPAD];
        const float* Ao = &A[o][0];
        float acc = 0.f;
        for (int c4 = 0; c4 < 32; ++c4) {
            const float4 h = hp4[c4];
            const float4 aa = *(const float4*)&Ao[4 * c4];
            acc += h.x * aa.x + h.y * aa.y + h.z * aa.z + h.w * aa.w;
        }
        povals[i] = rs * acc - mu * rs * K2[o] + K1[o];
    }
    __syncthreads();

    for (int i = T; i < 2560; i += 512) {
        const int t = i / 5, j = i - 5 * t;
        const int sl = idxL[t];
        const float4 v = *(const float4*)&povals[sl * 20 + 4 * j];
        *(float4*)&out[262144 + ((size_t)(b * 512 + t)) * 20 + 4 * j] = v;
    }
    for (int i = T; i < 512; i += 512) {
        const int sl = idxL[i];
        float2 v; v.x = subv[2 * sl]; v.y = subv[2 * sl + 1];
        *(float2*)&out[((size_t)(b * 512 + i)) * 2] = v;
    }
}

extern "C" void kernel_launch(void* const* d_in, const int* in_sizes, int n_in,
                              void* d_out, int out_size, void* d_ws, size_t ws_size,
                              hipStream_t stream) {
    (void)in_sizes; (void)n_in; (void)out_size; (void)ws_size;
    const int*   char_ids    = (const int*)d_in[0];
    const int*   word_ids    = (const int*)d_in[1];
    const int*   subject_ids = (const int*)d_in[2];
    const float* emb_char    = (const float*)d_in[3];
    const float* emb_word    = (const float*)d_in[4];
    const float* Wwc         = (const float*)d_in[5];
    const float* bwc         = (const float*)d_in[6];
    const float* l1_Wx       = (const float*)d_in[7];
    const float* l1_Wh       = (const float*)d_in[8];
    const float* l1_b        = (const float*)d_in[9];
    const float* l2_Wx       = (const float*)d_in[10];
    const float* l2_Wh       = (const float*)d_in[11];
    const float* l2_b        = (const float*)d_in[12];
    const float* beta_W      = (const float*)d_in[13];
    const float* beta_b      = (const float*)d_in[14];
    const float* gamma_W     = (const float*)d_in[15];
    const float* gamma_b     = (const float*)d_in[16];
    const float* sub_W       = (const float*)d_in[17];
    const float* sub_b       = (const float*)d_in[18];
    const float* po_W        = (const float*)d_in[19];
    const float* po_b        = (const float*)d_in[20];
    float* out = (float*)d_out;

    char* ws = (char*)d_ws;
    float* XW1 = (float*)(ws + 0);          // 20480 B (pad to 32768)
    uint4* WF  = (uint4*)(ws + 32768);      // 24576*16 = 393216 B -> ws 425984 B

    k_prep<<<dim3(58), dim3(512), 0, stream>>>(emb_char, emb_word, Wwc, bwc,
                                               l1_Wx, l1_b, l1_Wh, l2_Wx, l2_Wh,
                                               XW1, WF);
    k_lstm<<<dim3(256), dim3(512), 0, stream>>>(char_ids, word_ids, subject_ids,
                                                XW1, WF, l2_b,
                                                beta_W, beta_b, gamma_W, gamma_b,
                                                sub_W, sub_b, po_W, po_b, out);
}

// Round 10
// 203.959 us; speedup vs baseline: 1.2682x; 1.2682x over previous
//
#include <hip/hip_runtime.h>
#include <cstdint>
#include <cstddef>

// PointerNetwork: B=256, S=512, H=128, CHAR/CLASS=10, OUT=64, WE=32
// R11 = R6 verbatim (best measured: 115.6 us k_lstm / 203.25 us total).
// Post-R6 record: R7 (1-wave full pin), R8 (role-split 3-wave), R9 (explicit
// hybrid stream), R10 (phase-fused LDS reuse) ALL regressed via register-
// pressure-induced scratch spill (FETCH/WRITE explosion each time).
// R6's configuration -- 512 threads, 2 waves/SIMD, compiler-chosen weight
// residency, separated L2/L1 phases, 1 barrier/step -- is the empirical
// optimum for this structure.

#define HIST 128
#define HPAD 132

typedef _Float16 f16x8 __attribute__((ext_vector_type(8)));
typedef float    f32x4 __attribute__((ext_vector_type(4)));

__device__ __forceinline__ f16x8 as_h8(const uint4& v) {
    f16x8 r; __builtin_memcpy(&r, &v, 16); return r;
}

#define MFMA16(a, b, c) __builtin_amdgcn_mfma_f32_16x16x32_f16((a), (b), (c), 0, 0, 0)

__device__ __forceinline__ float fast_rcp(float x) {
#if __has_builtin(__builtin_amdgcn_rcpf)
    return __builtin_amdgcn_rcpf(x);
#else
    return 1.f / x;
#endif
}
__device__ __forceinline__ float sigm(float x) {
    x = fminf(fmaxf(x, -30.f), 30.f);
    return fast_rcp(1.f + __expf(-x));
}
__device__ __forceinline__ float tanh_fast(float x) {
    x = fminf(fmaxf(x, -15.f), 15.f);
    float e = __expf(-2.f * x);
    return (1.f - e) * fast_rcp(1.f + e);
}

// ---------------- P0: merged prep: XW1 table + MFMA B-frag packing -----------
// blocks 0..9: XW1 row for word id = blk.  blocks 10..57: pack WF.
// k_lstm thread thr = (w=thr>>6, l=thr&63); frag f: 0..31 L2 (j=f>>3, ks=f&7),
// 32..47 L1 (j=(f-32)>>2, ks=(f-32)&3). col = j*128 + 16*w + (l&15);
// elems e: k = ks*32 + 8*(l>>4) + e.
// L2 k<128 -> l2_Wh row k (h2 half), else l2_Wx row k-128 (h1n half).
__global__ __launch_bounds__(512) void k_prep(
    const float* __restrict__ emb_char, const float* __restrict__ emb_word,
    const float* __restrict__ Wwc, const float* __restrict__ bwc,
    const float* __restrict__ l1_Wx, const float* __restrict__ l1_b,
    const float* __restrict__ l1_Wh, const float* __restrict__ l2_Wx,
    const float* __restrict__ l2_Wh,
    float* __restrict__ XW1, uint4* __restrict__ WF)
{
    const int blk = blockIdx.x;
    const int T = threadIdx.x;
    if (blk < 10) {
        __shared__ float xw[64];
        if (T < 64) {
            float acc = emb_char[T] + bwc[T];   // emb_char row 0 (active steps have char==0)
            for (int m = 0; m < 32; ++m) acc += emb_word[blk * 32 + m] * Wwc[m * 64 + T];
            xw[T] = acc;
        }
        __syncthreads();
        float acc = l1_b[T];
        for (int k = 0; k < 64; ++k) acc += xw[k] * l1_Wx[k * 512 + T];
        XW1[blk * 512 + T] = acc;
    } else {
        const int gid = (blk - 10) * 512 + T;   // 0..24575 frags
        const int thr = gid / 48;
        const int f   = gid - thr * 48;
        const int w   = thr >> 6, l = thr & 63;
        const int kb  = 8 * (l >> 4);
        const bool isL2 = (f < 32);
        int j, ks;
        if (isL2) { j = f >> 3; ks = f & 7; }
        else      { const int f2 = f - 32; j = f2 >> 2; ks = f2 & 3; }
        const int col = j * 128 + 16 * w + (l & 15);
        union { uint4 qv; _Float16 h[8]; } o;
        for (int e = 0; e < 8; ++e) {
            const int k = ks * 32 + kb + e;
            float v;
            if (isL2) v = (k < 128) ? l2_Wh[k * 512 + col] : l2_Wx[(k - 128) * 512 + col];
            else      v = l1_Wh[k * 512 + col];
            o.h[e] = (_Float16)v;
        }
        WF[gid] = o.qv;   // gid == thr*48 + f
    }
}

// ---------------- main kernel: MFMA recurrence + fused epilogue --------------
__global__ __launch_bounds__(512, 2) void k_lstm(
    const int* __restrict__ char_ids, const int* __restrict__ word_ids,
    const int* __restrict__ subject_ids,
    const float* __restrict__ XW1, const uint4* __restrict__ WF,
    const float* __restrict__ l2_b,
    const float* __restrict__ beta_W, const float* __restrict__ beta_b,
    const float* __restrict__ gamma_W, const float* __restrict__ gamma_b,
    const float* __restrict__ sub_W, const float* __restrict__ sub_b,
    const float* __restrict__ po_W, const float* __restrict__ po_b,
    float* __restrict__ out)
{
    const int b    = blockIdx.x;
    const int T    = threadIdx.x;   // 0..511
    const int lane = T & 63;
    const int wv   = T >> 6;        // wave 0..7
    const int kb   = 8 * (lane >> 4);          // k-slab base within 32
    const int unit = 16 * wv + (lane & 15);    // this lane's unit (lanes<16 real)
    const bool g16 = (lane < 16);

    __shared__ int   charL[512];
    __shared__ int   wordL[512];
    __shared__ float XW1L[5120];                        // 10x512 XW1 table
    __shared__ __align__(16) _Float16 hcat[2][256];     // [h2 | h1n] dbuf
    __shared__ short wlist[512];
    __shared__ unsigned short idxL[512];
    __shared__ int   ccnt[8];
    __shared__ __align__(16) float hl[HIST * HPAD];     // h-history (f32)
    // epilogue workspace
    __shared__ float A[20][132];
    __shared__ float K1[20], K2[20];
    __shared__ float gm[128], bt[128];
    __shared__ float urs[HIST][2];
    __shared__ float povals[HIST * 20];
    __shared__ float subv[HIST * 2];
    __shared__ float swl[256];
    __shared__ float subj[256];

    charL[T] = char_ids[b * 512 + T];
    wordL[T] = word_ids[b * 512 + T];
#pragma unroll
    for (int i = 0; i < 10; ++i) XW1L[i * 512 + T] = XW1[i * 512 + T];
    __syncthreads();

    // compact active-step list (ordered) + slot map
    const bool act = (charL[T] == 0);
    const unsigned long long bmask = __ballot(act);
    if (lane == 0) ccnt[wv] = (int)__popcll(bmask);
    __syncthreads();
    int base = 0;
    for (int i = 0; i < wv; ++i) base += ccnt[i];
    int tot = base;
    for (int i = wv; i < 8; ++i) tot += ccnt[i];
    if (act) {
        const int pos = base + (int)__popcll(bmask & ((1ull << lane) - 1ull));
        wlist[pos] = (short)wordL[T];
    }
    {
        const int cin = base + (int)__popcll(bmask & ((2ull << lane) - 1ull));
        idxL[T] = (unsigned short)(cin < HIST - 1 ? cin : HIST - 1);
    }
    const int nact = tot;

    // init state
    if (T < 128) {
        hcat[0][T] = (_Float16)0.f;   // h2(-1) = 0
        hl[T]      = 0.f;             // slot 0 = zeros
    }
    float c1 = 0.f, c2 = 0.f;         // valid on lanes<16
    const float l2b0 = l2_b[unit];
    const float l2b1 = l2_b[128 + unit];
    const float l2b2 = l2_b[256 + unit];
    const float l2b3 = l2_b[384 + unit];

    // persistent MFMA B-fragments (48 x uint4 = 192 regs, AGPR-eligible;
    // residency left to the compiler -- every explicit scheme regressed)
    uint4 wf[48];
    {
        const uint4* p = WF + (size_t)T * 48;
#pragma unroll
        for (int i = 0; i < 48; ++i) wf[i] = p[i];
    }
    __syncthreads();

    // prologue: L1 gates for step 0 (h1 == 0 -> z = xw)
    if (nact > 0) {
        const int w0_ = wlist[0];
        const float zi = XW1L[w0_ * 512 + unit];
        const float zg = XW1L[w0_ * 512 + 256 + unit];
        const float zo = XW1L[w0_ * 512 + 384 + unit];
        c1 = sigm(zi) * tanh_fast(zg);            // c1_old == 0
        const float h1n = sigm(zo) * tanh_fast(c1);
        if (g16) hcat[0][128 + unit] = (_Float16)h1n;
        __syncthreads();
    }

    // superphase a: hcat[cur] = [h2(a-1) | h1n(a)].
    //   L2(a): z = bias + hcat[cur]*W2  -> h2(a) -> hcat[nxt][unit] + hl
    //   L1(a+1): z = xw(a+1) + h1n(a)*W1h -> h1n(a+1) -> hcat[nxt][128+unit]
    int cur = 0;
    for (int a = 0; a < nact; ++a) {
        const _Float16* hc = hcat[cur];
        _Float16*       hn = hcat[cur ^ 1];

        // ---- L2: 4 gate-tiles, K=256 chained MFMA ----
        f32x4 acc0 = {l2b0, 0.f, 0.f, 0.f};
        f32x4 acc1 = {l2b1, 0.f, 0.f, 0.f};
        f32x4 acc2 = {l2b2, 0.f, 0.f, 0.f};
        f32x4 acc3 = {l2b3, 0.f, 0.f, 0.f};
#pragma unroll
        for (int ks = 0; ks < 8; ++ks) {
            const f16x8 aa = *(const f16x8*)&hc[kb + 32 * ks];
            acc0 = MFMA16(aa, as_h8(wf[0 * 8 + ks]), acc0);
            acc1 = MFMA16(aa, as_h8(wf[1 * 8 + ks]), acc1);
            acc2 = MFMA16(aa, as_h8(wf[2 * 8 + ks]), acc2);
            acc3 = MFMA16(aa, as_h8(wf[3 * 8 + ks]), acc3);
        }
        if (g16) {
            c2 = sigm(acc1[0]) * c2 + sigm(acc0[0]) * tanh_fast(acc2[0]);
            const float h2v = sigm(acc3[0]) * tanh_fast(c2);
            hn[unit] = (_Float16)h2v;
            const int slot = (a + 1 < HIST - 1) ? a + 1 : HIST - 1;
            hl[slot * HPAD + unit] = h2v;
        }

        // ---- L1 for step a+1: K=128 over h1n(a) ----
        if (a + 1 < nact) {
            const int wid = wlist[a + 1];
            f32x4 r0 = {XW1L[wid * 512 + unit],       0.f, 0.f, 0.f};
            f32x4 r1 = {XW1L[wid * 512 + 128 + unit], 0.f, 0.f, 0.f};
            f32x4 r2 = {XW1L[wid * 512 + 256 + unit], 0.f, 0.f, 0.f};
            f32x4 r3 = {XW1L[wid * 512 + 384 + unit], 0.f, 0.f, 0.f};
#pragma unroll
            for (int ks = 0; ks < 4; ++ks) {
                const f16x8 aa = *(const f16x8*)&hc[128 + kb + 32 * ks];
                r0 = MFMA16(aa, as_h8(wf[32 + 0 * 4 + ks]), r0);
                r1 = MFMA16(aa, as_h8(wf[32 + 1 * 4 + ks]), r1);
                r2 = MFMA16(aa, as_h8(wf[32 + 2 * 4 + ks]), r2);
                r3 = MFMA16(aa, as_h8(wf[32 + 3 * 4 + ks]), r3);
            }
            if (g16) {
                c1 = sigm(r1[0]) * c1 + sigm(r0[0]) * tanh_fast(r2[0]);
                const float h1n = sigm(r3[0]) * tanh_fast(c1);
                hn[128 + unit] = (_Float16)h1n;
            }
        }
        __syncthreads();
        cur ^= 1;
    }

    // ================= fused epilogue (identical to R5) ======================
    if (T < 256) {
        swl[T] = sub_W[T];
        const int uu = T & 127, half = T >> 7;
        const int sidx = subject_ids[b * 2 + half];
        const int slot = idxL[sidx];
        subj[T] = hl[slot * HPAD + uu];
    }
    __syncthreads();

    if (T < 256) {
        const int uu = T & 127, half = T >> 7;
        const float* __restrict__ W = half ? gamma_W : beta_W;
        float acc = half ? gamma_b[uu] : beta_b[uu];
        for (int c = 0; c < 256; ++c) acc += subj[c] * W[c * 128 + uu];
        if (half) gm[uu] = acc;
        else      bt[uu] = acc;
    }
    __syncthreads();

    for (int i = T; i < 2560; i += 512) {
        const int o = i >> 7, c = i & 127;
        A[o][c] = gm[c] * po_W[c * 20 + o];
    }
    if (T < 20) {
        float k1 = po_b[T], k2 = 0.f;
        for (int c = 0; c < 128; ++c) {
            const float pw = po_W[c * 20 + T];
            k1 += bt[c] * pw;
            k2 += gm[c] * pw;
        }
        K1[T] = k1; K2[T] = k2;
    }
    const int nslot = (int)idxL[511] + 1;
    const float sb0 = sub_b[0], sb1 = sub_b[1];
    for (int s = T; s < nslot; s += 512) {
        const float4* hp4 = (const float4*)&hl[s * HPAD];
        float sum = 0.f, s2 = 0.f, sub0 = sb0, sub1 = sb1;
        for (int c4 = 0; c4 < 32; ++c4) {
            const float4 h = hp4[c4];
            sum += (h.x + h.y) + (h.z + h.w);
            s2  += h.x * h.x + h.y * h.y + h.z * h.z + h.w * h.w;
            const int c = 4 * c4;
            sub0 += h.x * swl[2 * c] + h.y * swl[2 * c + 2] + h.z * swl[2 * c + 4] + h.w * swl[2 * c + 6];
            sub1 += h.x * swl[2 * c + 1] + h.y * swl[2 * c + 3] + h.z * swl[2 * c + 5] + h.w * swl[2 * c + 7];
        }
        const float mu = sum * (1.f / 128.f);
        const float vv = fmaxf(s2 * (1.f / 128.f) - mu * mu, 0.f);
        urs[s][0] = mu;
        urs[s][1] = 1.f / sqrtf(vv + 1e-12f);
        subv[2 * s] = sub0; subv[2 * s + 1] = sub1;
    }
    __syncthreads();

    for (int i = T; i < nslot * 20; i += 512) {
        const int s = i / 20, o = i - 20 * s;
        const float mu = urs[s][0], rs = urs[s][1];
        const float4* hp4 = (const float4*)&hl[s * HPAD];
        const float* Ao = &A[o][0];
        float acc = 0.f;
        for (int c4 = 0; c4 < 32; ++c4) {
            const float4 h = hp4[c4];
            const float4 aa = *(const float4*)&Ao[4 * c4];
            acc += h.x * aa.x + h.y * aa.y + h.z * aa.z + h.w * aa.w;
        }
        povals[i] = rs * acc - mu * rs * K2[o] + K1[o];
    }
    __syncthreads();

    for (int i = T; i < 2560; i += 512) {
        const int t = i / 5, j = i - 5 * t;
        const int sl = idxL[t];
        const float4 v = *(const float4*)&povals[sl * 20 + 4 * j];
        *(float4*)&out[262144 + ((size_t)(b * 512 + t)) * 20 + 4 * j] = v;
    }
    for (int i = T; i < 512; i += 512) {
        const int sl = idxL[i];
        float2 v; v.x = subv[2 * sl]; v.y = subv[2 * sl + 1];
        *(float2*)&out[((size_t)(b * 512 + i)) * 2] = v;
    }
}

extern "C" void kernel_launch(void* const* d_in, const int* in_sizes, int n_in,
                              void* d_out, int out_size, void* d_ws, size_t ws_size,
                              hipStream_t stream) {
    (void)in_sizes; (void)n_in; (void)out_size; (void)ws_size;
    const int*   char_ids    = (const int*)d_in[0];
    const int*   word_ids    = (const int*)d_in[1];
    const int*   subject_ids = (const int*)d_in[2];
    const float* emb_char    = (const float*)d_in[3];
    const float* emb_word    = (const float*)d_in[4];
    const float* Wwc         = (const float*)d_in[5];
    const float* bwc         = (const float*)d_in[6];
    const float* l1_Wx       = (const float*)d_in[7];
    const float* l1_Wh       = (const float*)d_in[8];
    const float* l1_b        = (const float*)d_in[9];
    const float* l2_Wx       = (const float*)d_in[10];
    const float* l2_Wh       = (const float*)d_in[11];
    const float* l2_b        = (const float*)d_in[12];
    const float* beta_W      = (const float*)d_in[13];
    const float* beta_b      = (const float*)d_in[14];
    const float* gamma_W     = (const float*)d_in[15];
    const float* gamma_b     = (const float*)d_in[16];
    const float* sub_W       = (const float*)d_in[17];
    const float* sub_b       = (const float*)d_in[18];
    const float* po_W        = (const float*)d_in[19];
    const float* po_b        = (const float*)d_in[20];
    float* out = (float*)d_out;

    char* ws = (char*)d_ws;
    float* XW1 = (float*)(ws + 0);          // 20480 B (pad to 32768)
    uint4* WF  = (uint4*)(ws + 32768);      // 24576*16 = 393216 B -> ws 425984 B

    k_prep<<<dim3(58), dim3(512), 0, stream>>>(emb_char, emb_word, Wwc, bwc,
                                               l1_Wx, l1_b, l1_Wh, l2_Wx, l2_Wh,
                                               XW1, WF);
    k_lstm<<<dim3(256), dim3(512), 0, stream>>>(char_ids, word_ids, subject_ids,
                                                XW1, WF, l2_b,
                                                beta_W, beta_b, gamma_W, gamma_b,
                                                sub_W, sub_b, po_W, po_b, out);
}